// Round 1
// baseline (234.732 us; speedup 1.0000x reference)
//
#include <hip/hip_runtime.h>
#include <hip/hip_bf16.h>

#define C_IN  64
#define C_OUT 128
#define KK    27
#define HH    100000

typedef __attribute__((ext_vector_type(8))) short s8v;    // 8 bf16 = 4 VGPRs (MFMA A/B frag)
typedef __attribute__((ext_vector_type(4))) float f32x4;  // MFMA C/D frag

__device__ inline unsigned short f2bf(float f) {
    __hip_bfloat16 h = __float2bfloat16(f);
    return *reinterpret_cast<unsigned short*>(&h);
}

// ---------------- kernel 1: x (64,H) fp32 -> x_t (H,64) bf16 ----------------
__global__ __launch_bounds__(256) void transpose_kernel(const float* __restrict__ x,
                                                        unsigned short* __restrict__ xt) {
    __shared__ __align__(16) unsigned short ts[64 * 72];  // +8 pad
    const int tid = threadIdx.x;
    const int hbase = blockIdx.x * 64;
    #pragma unroll
    for (int it = 0; it < 16; ++it) {
        int i = it * 256 + tid;           // 64h x 64c
        int c = i >> 6, hl = i & 63;
        int hg = hbase + hl;
        float v = (hg < HH) ? x[(size_t)c * HH + hg] : 0.f;  // coalesced in h
        ts[hl * 72 + c] = f2bf(v);
    }
    __syncthreads();
    #pragma unroll
    for (int it = 0; it < 2; ++it) {
        int u = it * 256 + tid;           // 64 rows x 8 chunks of 16B
        int hl = u >> 3, part = u & 7;
        int hg = hbase + hl;
        if (hg < HH)
            *(int4*)&xt[(size_t)hg * 64 + part * 8] = *(const int4*)&ts[hl * 72 + part * 8];
    }
}

// -------- kernel 2: W (o,c,k) fp32 -> wk (k,o,c) bf16 (tiny, 221184 elems) --------
__global__ __launch_bounds__(256) void wconv_kernel(const float* __restrict__ w,
                                                    unsigned short* __restrict__ wk) {
    int t = blockIdx.x * 256 + threadIdx.x;
    if (t < KK * C_OUT * C_IN) {
        int c = t & 63, o = (t >> 6) & 127, k = t >> 13;
        wk[t] = f2bf(w[(size_t)o * (C_IN * KK) + c * KK + k]);
    }
}

// ---------------- kernel 3: main gather-GEMM ----------------
// block: 256 thr = 4 waves; tile M=128 (all o) x N=128 h; wave w: h sub-tile [w*32, w*32+32)
__global__ __launch_bounds__(256) void conv_main(const unsigned short* __restrict__ xt,
                                                 const unsigned short* __restrict__ wk,
                                                 const int* __restrict__ neigh,
                                                 float* __restrict__ out) {
    __shared__ int neigh_s[128 * KK];                         // 13824 B
    __shared__ __align__(16) unsigned short w_s[128 * 72];    // 18432 B (+8 pad/row)
    __shared__ __align__(16) unsigned short c_s[128 * 72];    // 18432 B (+8 pad/row)

    const int tid  = threadIdx.x;
    const int wave = tid >> 6;
    const int lane = tid & 63;
    const int col  = lane & 15;   // N index (h) in C/D; also M index for A-frag reads
    const int quad = lane >> 4;
    const int nb   = wave * 32;
    const int hbase = blockIdx.x * 128;

    // stage neighbor indices for the block's 128 h
    for (int i = tid; i < 128 * KK; i += 256) {
        int hl = i / KK, kx = i - hl * KK;
        int hg = hbase + hl;
        neigh_s[i] = (hg < HH) ? neigh[(size_t)hg * KK + kx] : -1;
    }

    f32x4 acc[8][2];
    #pragma unroll
    for (int mt = 0; mt < 8; ++mt)
        #pragma unroll
        for (int nt = 0; nt < 2; ++nt)
            acc[mt][nt] = (f32x4){0.f, 0.f, 0.f, 0.f};

    __syncthreads();

    for (int k = 0; k < KK; ++k) {
        // stage W k-slice: wk[k][o][c] -> w_s[o][c] (8192 bf16, 16B chunks)
        {
            const int4* src = (const int4*)(wk + (size_t)k * (C_OUT * C_IN));
            #pragma unroll
            for (int it = 0; it < 4; ++it) {
                int i = it * 256 + tid;       // chunk id, 8 bf16 each
                int o = i >> 3, cc = i & 7;
                *(int4*)&w_s[o * 72 + cc * 8] = src[i];
            }
        }
        // gather 128 columns of x_t (128 B each) -> c_s[h][c]
        {
            #pragma unroll
            for (int it = 0; it < 2; ++it) {
                int u = it * 256 + tid;       // 128 h x 4 parts of 32B
                int hl = u >> 2, part = u & 3;
                int idx = neigh_s[hl * KK + k];
                int4 v0, v1;
                if (idx >= 0) {
                    const int4* src = (const int4*)(xt + (size_t)idx * 64 + part * 16);
                    v0 = src[0];
                    v1 = src[1];
                } else {
                    v0 = make_int4(0, 0, 0, 0);
                    v1 = make_int4(0, 0, 0, 0);
                }
                *(int4*)&c_s[hl * 72 + part * 16]     = v0;
                *(int4*)&c_s[hl * 72 + part * 16 + 8] = v1;
            }
        }
        __syncthreads();

        // 2 K-chunks of 32 (c-halves); B-frag shared over 8 m-tiles, A-frag over 2 n-tiles
        #pragma unroll
        for (int ch = 0; ch < 2; ++ch) {
            s8v b0 = *(const s8v*)&c_s[(nb + col) * 72 + ch * 32 + quad * 8];
            s8v b1 = *(const s8v*)&c_s[(nb + 16 + col) * 72 + ch * 32 + quad * 8];
            #pragma unroll
            for (int mt = 0; mt < 8; ++mt) {
                s8v a = *(const s8v*)&w_s[(mt * 16 + col) * 72 + ch * 32 + quad * 8];
                acc[mt][0] = __builtin_amdgcn_mfma_f32_16x16x32_bf16(a, b0, acc[mt][0], 0, 0, 0);
                acc[mt][1] = __builtin_amdgcn_mfma_f32_16x16x32_bf16(a, b1, acc[mt][1], 0, 0, 0);
            }
        }
        __syncthreads();
    }

    // epilogue: D row = quad*4+reg (o), col = lane&15 (h); relu + store fp32
    #pragma unroll
    for (int mt = 0; mt < 8; ++mt) {
        #pragma unroll
        for (int nt = 0; nt < 2; ++nt) {
            int hg = hbase + nb + nt * 16 + col;
            if (hg < HH) {
                #pragma unroll
                for (int r = 0; r < 4; ++r) {
                    int o = mt * 16 + quad * 4 + r;
                    float v = acc[mt][nt][r];
                    out[(size_t)o * HH + hg] = v > 0.f ? v : 0.f;
                }
            }
        }
    }
}

extern "C" void kernel_launch(void* const* d_in, const int* in_sizes, int n_in,
                              void* d_out, int out_size, void* d_ws, size_t ws_size,
                              hipStream_t stream) {
    const float* data_in = (const float*)d_in[0];
    const int*   neigh   = (const int*)d_in[1];
    const float* weight  = (const float*)d_in[2];
    float* out = (float*)d_out;

    unsigned short* xt = (unsigned short*)d_ws;            // H*64 bf16 = 12.8 MB
    unsigned short* wk = xt + (size_t)HH * 64;             // 27*128*64 bf16 = 442 KB

    transpose_kernel<<<(HH + 63) / 64, 256, 0, stream>>>(data_in, xt);
    wconv_kernel<<<(KK * C_OUT * C_IN + 255) / 256, 256, 0, stream>>>(weight, wk);
    conv_main<<<(HH + 127) / 128, 256, 0, stream>>>(xt, wk, neigh, out);
}